// Round 11
// baseline (156.447 us; speedup 1.0000x reference)
//
#include <hip/hip_runtime.h>
#include <hip/hip_bf16.h>
#include <stdint.h>

typedef unsigned short u16;
typedef short bf16x8 __attribute__((ext_vector_type(8)));
typedef float f32x4 __attribute__((ext_vector_type(4)));

#define GLOAD16(gp, lp) __builtin_amdgcn_global_load_lds( \
    (const __attribute__((address_space(1))) uint32_t*)(gp), \
    (__attribute__((address_space(3))) uint32_t*)(lp), 16, 0, 0)

#define VMCNT10 do { asm volatile("s_waitcnt vmcnt(10)" ::: "memory"); \
                     __builtin_amdgcn_sched_barrier(0); } while (0)
#define SBAR    do { __builtin_amdgcn_s_barrier(); \
                     __builtin_amdgcn_sched_barrier(0); } while (0)
#define LGKM0   do { asm volatile("s_waitcnt lgkmcnt(0)" ::: "memory"); \
                     __builtin_amdgcn_sched_barrier(0); } while (0)

__device__ __forceinline__ u16 f2bf(float f) {
  union { float f; uint32_t u; } x; x.f = f;
  return (u16)((x.u + 0x7FFFu + ((x.u >> 16) & 1u)) >> 16);
}
__device__ __forceinline__ float bf2f(u16 h) {
  union { uint32_t u; float f; } x; x.u = (uint32_t)h << 16;
  return x.f;
}

// Bijective XCD-chunked block swizzle (T1, m204 form). Requires nwg % 8 == 0.
__device__ __forceinline__ void xcd_swizzle(int& bx, int& by, int& bz) {
  const int gx = gridDim.x, gy = gridDim.y;
  const int nwg = gx * gy * (int)gridDim.z;
  const int lin = ((int)blockIdx.z * gy + (int)blockIdx.y) * gx + (int)blockIdx.x;
  const int q = nwg >> 3;
  const int wl = (lin & 7) * q + (lin >> 3);
  bz = wl / (gx * gy);
  const int rem = wl - bz * gx * gy;
  by = rem / gx;
  bx = rem - by * gx;
}

// ------- streaming cast (no x transpose here) -------
// blocks 0..2047   : x -> xb, pure row streaming
// blocks 2048..3583: wq/wk/wv plain cast, streaming
// blocks 3584..3839: wo transpose (64x64 f32 tiles, 4 MB only)
__global__ __launch_bounds__(256) void cast_stream(const float* __restrict__ x,
                                                   const float* __restrict__ wq,
                                                   const float* __restrict__ wk,
                                                   const float* __restrict__ wv,
                                                   const float* __restrict__ wo,
                                                   u16* __restrict__ xb,
                                                   u16* __restrict__ WA,
                                                   u16* __restrict__ WBb) {
  __shared__ float tile[64][65];
  const int lin = blockIdx.x;
  const int t = threadIdx.x;
  if (lin < 2048) {
    const float* src = x + (size_t)lin * 8192;
    u16* dst = xb + (size_t)lin * 8192;
#pragma unroll
    for (int i = 0; i < 4; ++i) {
      const int e = i * 2048 + t * 8;
      float4 a = *(const float4*)&src[e];
      float4 b = *(const float4*)&src[e + 4];
      u16 p[8];
      p[0] = f2bf(a.x); p[1] = f2bf(a.y); p[2] = f2bf(a.z); p[3] = f2bf(a.w);
      p[4] = f2bf(b.x); p[5] = f2bf(b.y); p[6] = f2bf(b.z); p[7] = f2bf(b.w);
      *(uint4*)&dst[e] = *(const uint4*)p;
    }
  } else if (lin < 3584) {
    const int e0 = (lin - 2048) * 2048 + t * 8;
    const int w = e0 >> 20;
    const int loc = e0 & 1048575;
    const float* in = w == 0 ? wq : w == 1 ? wk : wv;
    u16* o = w == 0 ? WA : w == 1 ? WBb : WBb + 1048576;
    float4 a = *(const float4*)&in[loc];
    float4 b = *(const float4*)&in[loc + 4];
    u16 p[8];
    p[0] = f2bf(a.x); p[1] = f2bf(a.y); p[2] = f2bf(a.z); p[3] = f2bf(a.w);
    p[4] = f2bf(b.x); p[5] = f2bf(b.y); p[6] = f2bf(b.z); p[7] = f2bf(b.w);
    *(uint4*)&o[loc] = *(const uint4*)p;
  } else {
    const int w2 = lin - 3584;
    const int r0 = (w2 >> 4) * 64, c0 = (w2 & 15) * 64;
    const int lr = t >> 2, lc = (t & 3) * 16;
    const float* src = wo + (size_t)(r0 + lr) * 1024 + c0 + lc;
#pragma unroll
    for (int j = 0; j < 4; ++j) {
      float4 v = *(const float4*)&src[j * 4];
      tile[lr][lc + j * 4 + 0] = v.x;
      tile[lr][lc + j * 4 + 1] = v.y;
      tile[lr][lc + j * 4 + 2] = v.z;
      tile[lr][lc + j * 4 + 3] = v.w;
    }
    __syncthreads();
    u16 tr[16];
#pragma unroll
    for (int j = 0; j < 16; ++j) tr[j] = f2bf(tile[lc + j][lr]);
    u16* dst = WA + 1048576 + (size_t)(c0 + lr) * 1024 + r0 + lc;
    *(uint4*)&dst[0] = *(const uint4*)&tr[0];
    *(uint4*)&dst[8] = *(const uint4*)&tr[8];
  }
}

// ------- blocked transpose: xb -> xTt[dtile(8)][tchunk(256)] tiles -------
// Each tile = contiguous 16 KB [128 d][64 t] bf16 row-major (d rows, 64 t).
// Reads 64 x 256 B rows of xb (L2/L3-hot); writes one contiguous 16 KB chunk.
__global__ __launch_bounds__(256) void transpose_x(const u16* __restrict__ xb,
                                                   u16* __restrict__ xTt) {
  __shared__ u16 ldsT[128][72];   // stride 72 u16 = 144 B (16B-aligned, spreads banks)
  const int tile = blockIdx.x;
  const int dtile = tile >> 8, tchunk = tile & 255;
  const int t = threadIdx.x;
  const int lr = t >> 2;          // t-row 0..63
  const int dq = (t & 3) * 32;    // d quarter
  const u16* src = xb + (size_t)(tchunk * 64 + lr) * 1024 + dtile * 128 + dq;
#pragma unroll
  for (int i = 0; i < 4; ++i) {
    u16 v[8];
    *(uint4*)v = *(const uint4*)&src[i * 8];
#pragma unroll
    for (int j = 0; j < 8; ++j) ldsT[dq + i * 8 + j][lr] = v[j];
  }
  __syncthreads();
  const int d = t >> 1, seg = (t & 1) * 32;
  u16* dst = xTt + (size_t)tile * 8192 + d * 64 + seg;
#pragma unroll
  for (int i = 0; i < 4; ++i)
    *(uint4*)&dst[i * 8] = *(const uint4*)&ldsT[d][seg + i * 8];
}

// ------- fused: triangular Gram split-K (576 blocks) + W12 GEMM (128 blocks) ----
// 8-wave 128^2 NT inner loop, K=1024.
// Gram operands come from blocked xTt tiles: lda=64, kt-step=+8192 elems.
__global__ __launch_bounds__(512) void gram_w12(const u16* __restrict__ xTt,
                                                u16* __restrict__ Gp,
                                                const u16* __restrict__ WA,
                                                const u16* __restrict__ WBb,
                                                u16* __restrict__ W12) {
  __shared__ u16 lds[2 * 8192];
  const int lin = blockIdx.x;
  const int wl = (lin & 7) * 88 + (lin >> 3);   // 704/8 = 88, bijective
  const u16 *Abase, *Bbase;
  u16* Cb;
  int lda, sKt, ldc;
  if (wl < 576) {
    const int z = wl / 36, t5 = wl - z * 36;
    const int b = z >> 2, kc = z & 3;
    int ti = 0;
    while ((ti + 1) * (ti + 2) / 2 <= t5) ++ti;
    const int tj = t5 - ti * (ti + 1) / 2;
    const int tc0 = b * 64 + kc * 16;           // first t-chunk of this z-slice
    Abase = xTt + (size_t)(ti * 256 + tc0) * 8192;
    Bbase = xTt + (size_t)(tj * 256 + tc0) * 8192;
    lda = 64; sKt = 8192;
    Cb = Gp + ((size_t)z * 36 + t5) * 16384;
    ldc = 128;
  } else {
    const int w = wl - 576;
    const int z2 = w >> 6, tl = w & 63;
    const int by = tl >> 3, bx = tl & 7;
    Abase = WA + (size_t)z2 * 1048576 + (size_t)(by * 128) * 1024;
    Bbase = WBb + (size_t)z2 * 1048576 + (size_t)(bx * 128) * 1024;
    lda = 1024; sKt = 64;
    Cb = W12 + (size_t)z2 * 1048576 + (size_t)(by * 128) * 1024 + bx * 128;
    ldc = 1024;
  }

  const int t = threadIdx.x;
  const int l = t & 63;
  const int wid = t >> 6;
  const int wr = wid >> 2, wc = wid & 3;
  const int lr16 = l & 15, hi = l >> 4;

  f32x4 acc[4][2];
#pragma unroll
  for (int m = 0; m < 4; ++m)
#pragma unroll
    for (int n = 0; n < 2; ++n) acc[m][n] = (f32x4){0.f, 0.f, 0.f, 0.f};

  for (int s = 0; s < 16; ++s) {
    __syncthreads();
    const u16* As = Abase + (size_t)s * sKt;
    const u16* Bs = Bbase + (size_t)s * sKt;
#pragma unroll
    for (int i = 0; i < 2; ++i) {
      int slot = i * 512 + t;
      int row = slot >> 3, cp = slot & 7;
      int clog = cp ^ (row & 7);
      GLOAD16(As + (size_t)row * lda + clog * 8, &lds[slot * 8]);
    }
#pragma unroll
    for (int i = 0; i < 2; ++i) {
      int slot = i * 512 + t;
      int row = slot >> 3, cp = slot & 7;
      int clog = cp ^ (row & 7);
      GLOAD16(Bs + (size_t)row * lda + clog * 8, &lds[8192 + slot * 8]);
    }
    asm volatile("s_waitcnt vmcnt(0)" ::: "memory");
    __syncthreads();
#pragma unroll
    for (int ks = 0; ks < 2; ++ks) {
      bf16x8 af[4], bfr[2];
#pragma unroll
      for (int m = 0; m < 4; ++m) {
        int row = wr * 64 + m * 16 + lr16;
        int p = (ks * 4 + hi) ^ (row & 7);
        af[m] = *(const bf16x8*)&lds[row * 64 + p * 8];
      }
#pragma unroll
      for (int n = 0; n < 2; ++n) {
        int row = wc * 32 + n * 16 + lr16;
        int p = (ks * 4 + hi) ^ (row & 7);
        bfr[n] = *(const bf16x8*)&lds[8192 + row * 64 + p * 8];
      }
#pragma unroll
      for (int m = 0; m < 4; ++m)
#pragma unroll
        for (int n = 0; n < 2; ++n)
          acc[m][n] = __builtin_amdgcn_mfma_f32_16x16x32_bf16(af[m], bfr[n], acc[m][n], 0, 0, 0);
    }
  }

#pragma unroll
  for (int m = 0; m < 4; ++m) {
    int row0 = wr * 64 + m * 16 + hi * 4;
#pragma unroll
    for (int n = 0; n < 2; ++n) {
      int col = wc * 32 + n * 16 + lr16;
      f32x4 v = acc[m][n];
#pragma unroll
      for (int r = 0; r < 4; ++r) Cb[(size_t)(row0 + r) * ldc + col] = f2bf(v[r]);
    }
  }
}

// ------- 8-wave 128^2 batched NT GEMM (small matrices) ----
__global__ __launch_bounds__(512) void gemm_bt8(const u16* __restrict__ A,
                                                const u16* __restrict__ B,
                                                u16* __restrict__ C,
                                                int lda, int ldb, int ldc, int K,
                                                size_t sA, size_t sB, size_t sC) {
  __shared__ u16 lds[2 * 8192];
  int bx, by, bz;
  xcd_swizzle(bx, by, bz);
  A += (size_t)bz * sA;
  B += (size_t)bz * sB;
  const int t = threadIdx.x;
  const int l = t & 63;
  const int wid = t >> 6;
  const int wr = wid >> 2, wc = wid & 3;
  const int lr16 = l & 15, hi = l >> 4;
  const int mBase = by * 128;
  const int nBase = bx * 128;

  f32x4 acc[4][2];
#pragma unroll
  for (int m = 0; m < 4; ++m)
#pragma unroll
    for (int n = 0; n < 2; ++n) acc[m][n] = (f32x4){0.f, 0.f, 0.f, 0.f};

  for (int kt = 0; kt < K; kt += 64) {
    __syncthreads();
#pragma unroll
    for (int i = 0; i < 2; ++i) {
      int s = i * 512 + t;
      int row = s >> 3, cp = s & 7;
      int clog = cp ^ (row & 7);
      GLOAD16(A + (size_t)(mBase + row) * lda + kt + clog * 8, &lds[s * 8]);
    }
#pragma unroll
    for (int i = 0; i < 2; ++i) {
      int s = i * 512 + t;
      int row = s >> 3, cp = s & 7;
      int clog = cp ^ (row & 7);
      GLOAD16(B + (size_t)(nBase + row) * ldb + kt + clog * 8, &lds[8192 + s * 8]);
    }
    asm volatile("s_waitcnt vmcnt(0)" ::: "memory");
    __syncthreads();
#pragma unroll
    for (int ks = 0; ks < 2; ++ks) {
      bf16x8 af[4], bfr[2];
#pragma unroll
      for (int m = 0; m < 4; ++m) {
        int row = wr * 64 + m * 16 + lr16;
        int p = (ks * 4 + hi) ^ (row & 7);
        af[m] = *(const bf16x8*)&lds[row * 64 + p * 8];
      }
#pragma unroll
      for (int n = 0; n < 2; ++n) {
        int row = wc * 32 + n * 16 + lr16;
        int p = (ks * 4 + hi) ^ (row & 7);
        bfr[n] = *(const bf16x8*)&lds[8192 + row * 64 + p * 8];
      }
#pragma unroll
      for (int m = 0; m < 4; ++m)
#pragma unroll
        for (int n = 0; n < 2; ++n)
          acc[m][n] = __builtin_amdgcn_mfma_f32_16x16x32_bf16(af[m], bfr[n], acc[m][n], 0, 0, 0);
    }
  }

#pragma unroll
  for (int m = 0; m < 4; ++m) {
    int row0 = mBase + wr * 64 + m * 16 + hi * 4;
#pragma unroll
    for (int n = 0; n < 2; ++n) {
      int col = nBase + wc * 32 + n * 16 + lr16;
      f32x4 v = acc[m][n];
      u16* Cb = C + (size_t)bz * sC;
#pragma unroll
      for (int r = 0; r < 4; ++r) Cb[(size_t)(row0 + r) * ldc + col] = f2bf(v[r]);
    }
  }
}

// ------- reduce 4 kc-partials of tile t, write G + mirrored transpose -------
__global__ __launch_bounds__(256) void reduce_mirror(const u16* __restrict__ Gp,
                                                     u16* __restrict__ G) {
  __shared__ u16 ldsT[128][136];
  const int t5 = blockIdx.x;       // 0..35
  const int b = blockIdx.y;        // 0..3
  int ti = 0;
  while ((ti + 1) * (ti + 2) / 2 <= t5) ++ti;
  const int tj = t5 - ti * (ti + 1) / 2;
  const int tid = threadIdx.x;
  const int rr = tid >> 4, ccc = (tid & 15) * 8;
  u16* Gb = G + (size_t)b * 1048576;
  const size_t ZS = (size_t)36 * 16384;
  const u16* base = Gp + ((size_t)(b * 4) * 36 + t5) * 16384;
#pragma unroll
  for (int i = 0; i < 8; ++i) {
    int row = i * 16 + rr;
    const u16* p = base + row * 128 + ccc;
    u16 a0[8], a1[8], a2[8], a3[8], o[8];
    *(uint4*)a0 = *(const uint4*)&p[0];
    *(uint4*)a1 = *(const uint4*)&p[ZS];
    *(uint4*)a2 = *(const uint4*)&p[2 * ZS];
    *(uint4*)a3 = *(const uint4*)&p[3 * ZS];
#pragma unroll
    for (int j = 0; j < 8; ++j)
      o[j] = f2bf(bf2f(a0[j]) + bf2f(a1[j]) + bf2f(a2[j]) + bf2f(a3[j]));
    *(uint4*)&Gb[(size_t)(ti * 128 + row) * 1024 + tj * 128 + ccc] = *(const uint4*)o;
    *(uint4*)&ldsT[row][ccc] = *(const uint4*)o;
  }
  if (ti != tj) {
    __syncthreads();
#pragma unroll
    for (int i = 0; i < 8; ++i) {
      int row = i * 16 + rr;
      u16 m8[8];
#pragma unroll
      for (int j = 0; j < 8; ++j) m8[j] = ldsT[ccc + j][row];
      *(uint4*)&Gb[(size_t)(tj * 128 + row) * 1024 + ti * 128 + ccc] = *(const uint4*)m8;
    }
  }
}

// =================== 256^2 8-phase NT GEMM core ===================
template <bool F32OUT>
__device__ __forceinline__ void gemm256_core(const u16* __restrict__ A,
                                             const u16* __restrict__ B,
                                             void* __restrict__ C,
                                             int lda, int ldb, int ldc, int K,
                                             int mBase, int nBase, u16* lds) {
  const int t = threadIdx.x;
  const int l = t & 63;
  const int wid = t >> 6;
  const int wr = wid >> 2;
  const int wc = wid & 3;
  const int lr16 = l & 15, hi = l >> 4;
  const int rl0 = t >> 3;
  const int rl1 = rl0 + 64;
  const int cp  = t & 7;
  const int cs  = cp ^ (rl0 & 7);
  const int NT = K >> 6;

  f32x4 acc[8][4];
#pragma unroll
  for (int m = 0; m < 8; ++m)
#pragma unroll
    for (int n = 0; n < 4; ++n) acc[m][n] = (f32x4){0.f, 0.f, 0.f, 0.f};

  auto stage = [&](const u16* g0, int ld, u16* d) {
    GLOAD16(g0 + (size_t)rl0 * ld + cs * 8, d + rl0 * 64 + cp * 8);
    GLOAD16(g0 + (size_t)rl1 * ld + cs * 8, d + rl1 * 64 + cp * 8);
  };
  stage(A + (size_t)mBase * lda,          lda, lds + 0);
  stage(B + (size_t)nBase * ldb,          ldb, lds + 16384);
  stage(B + (size_t)(nBase + 128) * ldb,  ldb, lds + 24576);
  stage(A + (size_t)(mBase + 128) * lda,  lda, lds + 8192);
  stage(B + (size_t)nBase * ldb + 64,         ldb, lds + 32768 + 16384);
  stage(A + (size_t)mBase * lda + 64,         lda, lds + 32768);
  stage(B + (size_t)(nBase + 128) * ldb + 64, ldb, lds + 32768 + 24576);

  bf16x8 af[4][2], b0[2][2], b1[2][2];

  for (int tt = 0; tt < NT; ++tt) {
    const int cur = tt & 1;
    u16* bufA = lds + cur * 32768;
    u16* bufB = bufA + 16384;
    u16* bufN = lds + ((tt + 1) & 1) * 32768;
    int t1 = tt + 1; if (t1 >= NT) t1 -= NT;
    int t2 = tt + 2; if (t2 >= NT) t2 -= NT;
    const int k1 = t1 * 64, k2 = t2 * 64;

    // phase 1: (mh0, nh0)
    VMCNT10;
    SBAR;
    stage(A + (size_t)(mBase + 128) * lda + k1, lda, bufN + 8192);
#pragma unroll
    for (int mi = 0; mi < 4; ++mi) {
      int row = wr * 64 + mi * 16 + lr16;
#pragma unroll
      for (int kk = 0; kk < 2; ++kk) {
        int p = (kk * 4 + hi) ^ (row & 7);
        af[mi][kk] = *(const bf16x8*)&bufA[row * 64 + p * 8];
      }
    }
#pragma unroll
    for (int ni = 0; ni < 2; ++ni) {
      int row = wc * 32 + ni * 16 + lr16;
#pragma unroll
      for (int kk = 0; kk < 2; ++kk) {
        int p = (kk * 4 + hi) ^ (row & 7);
        b0[ni][kk] = *(const bf16x8*)&bufB[row * 64 + p * 8];
      }
    }
    LGKM0;
    __builtin_amdgcn_s_setprio(1);
#pragma unroll
    for (int kk = 0; kk < 2; ++kk)
#pragma unroll
      for (int mi = 0; mi < 4; ++mi)
#pragma unroll
        for (int ni = 0; ni < 2; ++ni)
          acc[mi][ni] = __builtin_amdgcn_mfma_f32_16x16x32_bf16(af[mi][kk], b0[ni][kk], acc[mi][ni], 0, 0, 0);
    __builtin_amdgcn_s_setprio(0);

    // phase 2: (mh0, nh1)
    VMCNT10;
    SBAR;
    stage(B + (size_t)nBase * ldb + k2, ldb, bufB);
#pragma unroll
    for (int ni = 0; ni < 2; ++ni) {
      int row = 128 + wc * 32 + ni * 16 + lr16;
#pragma unroll
      for (int kk = 0; kk < 2; ++kk) {
        int p = (kk * 4 + hi) ^ (row & 7);
        b1[ni][kk] = *(const bf16x8*)&bufB[row * 64 + p * 8];
      }
    }
    LGKM0;
    __builtin_amdgcn_s_setprio(1);
#pragma unroll
    for (int kk = 0; kk < 2; ++kk)
#pragma unroll
      for (int mi = 0; mi < 4; ++mi)
#pragma unroll
        for (int ni = 0; ni < 2; ++ni)
          acc[mi][2 + ni] = __builtin_amdgcn_mfma_f32_16x16x32_bf16(af[mi][kk], b1[ni][kk], acc[mi][2 + ni], 0, 0, 0);
    __builtin_amdgcn_s_setprio(0);

    // phase 3: (mh1, nh1)
    VMCNT10;
    SBAR;
    stage(A + (size_t)mBase * lda + k2, lda, bufA);
#pragma unroll
    for (int mi = 0; mi < 4; ++mi) {
      int row = 128 + wr * 64 + mi * 16 + lr16;
#pragma unroll
      for (int kk = 0; kk < 2; ++kk) {
        int p = (kk * 4 + hi) ^ (row & 7);
        af[mi][kk] = *(const bf16x8*)&bufA[row * 64 + p * 8];
      }
    }
    LGKM0;
    __builtin_amdgcn_s_setprio(1);
#pragma unroll
    for (int kk = 0; kk < 2; ++kk)
#pragma unroll
      for (int mi = 0; mi < 4; ++mi)
#pragma unroll
        for (int ni = 0; ni < 2; ++ni)
          acc[4 + mi][2 + ni] = __builtin_amdgcn_mfma_f32_16x16x32_bf16(af[mi][kk], b1[ni][kk], acc[4 + mi][2 + ni], 0, 0, 0);
    __builtin_amdgcn_s_setprio(0);

    // phase 4: (mh1, nh0)
    SBAR;
    stage(B + (size_t)(nBase + 128) * ldb + k2, ldb, bufB + 8192);
    __builtin_amdgcn_s_setprio(1);
#pragma unroll
    for (int kk = 0; kk < 2; ++kk)
#pragma unroll
      for (int mi = 0; mi < 4; ++mi)
#pragma unroll
        for (int ni = 0; ni < 2; ++ni)
          acc[4 + mi][ni] = __builtin_amdgcn_mfma_f32_16x16x32_bf16(af[mi][kk], b0[ni][kk], acc[4 + mi][ni], 0, 0, 0);
    __builtin_amdgcn_s_setprio(0);
  }

#pragma unroll
  for (int m = 0; m < 8; ++m) {
    int row0 = mBase + (m >> 2) * 128 + wr * 64 + (m & 3) * 16 + hi * 4;
#pragma unroll
    for (int n = 0; n < 4; ++n) {
      int col = nBase + (n >> 1) * 128 + wc * 32 + (n & 1) * 16 + lr16;
      f32x4 v = acc[m][n];
      if (F32OUT) {
        float* Cf = (float*)C;
#pragma unroll
        for (int r = 0; r < 4; ++r) Cf[(size_t)(row0 + r) * ldc + col] = v[r];
      } else {
        u16* Cb = (u16*)C;
#pragma unroll
        for (int r = 0; r < 4; ++r) Cb[(size_t)(row0 + r) * ldc + col] = f2bf(v[r]);
      }
    }
  }
}

// out_b = x_b @ P_b : grid (4,64).
__global__ __launch_bounds__(512) void gemm256_out(const u16* __restrict__ xb,
                                                   const u16* __restrict__ PT,
                                                   float* __restrict__ out) {
  __shared__ u16 lds[65536];
  int bx, by, bz;
  xcd_swizzle(bx, by, bz);
  const u16* Bp = PT + (size_t)(by >> 4) * 1048576;
  gemm256_core<true>(xb, Bp, out, 1024, 1024, 1024, 1024, by * 256, bx * 256, lds);
}

// ---------------- host-side orchestration ----------------
// out_b = x_b @ W1 @ G_b @ W2 ; W1 = wq wk^T, W2 = wv wo, G_b = x_b^T x_b.
extern "C" void kernel_launch(void* const* d_in, const int* in_sizes, int n_in,
                              void* d_out, int out_size, void* d_ws, size_t ws_size,
                              hipStream_t stream) {
  const float* x  = (const float*)d_in[0];
  const float* wq = (const float*)d_in[1];
  const float* wk = (const float*)d_in[2];
  const float* wv = (const float*)d_in[3];
  const float* wo = (const float*)d_in[4];
  float* out = (float*)d_out;

  u16* ws = (u16*)d_ws;
  const size_t MW = 1048576;
  u16* xb  = ws;                    // [16384][1024]
  u16* xTt = ws + 16 * MW;          // [8 dtile][256 tchunk] x 16KB blocked tiles
  u16* WA  = ws + 32 * MW;          // [wq][woT]
  u16* WBb = ws + 34 * MW;          // [wk][wv]
  u16* W12 = ws + 36 * MW;          // [W1][W2T]
  u16* G   = ws + 38 * MW;          // [4][1024][1024]
  u16* S   = ws + 42 * MW;          // [4]
  u16* PT  = ws + 46 * MW;          // [4]
  u16* Gp  = ws + 50 * MW;          // [16][36][128][128] bf16 tri partials

  // pure streaming casts
  cast_stream<<<3840, 256, 0, stream>>>(x, wq, wk, wv, wo, xb, WA, WBb);
  // blocked transpose xb -> xTt (contiguous 16 KB tile writes)
  transpose_x<<<2048, 256, 0, stream>>>(xb, xTt);

  // fused: triangular Gram split-K (576) + W12 GEMM (128)
  gram_w12<<<704, 512, 0, stream>>>(xTt, Gp, WA, WBb, W12);
  reduce_mirror<<<dim3(36, 4), 256, 0, stream>>>(Gp, G);

  // S_b = NT(W2T, G_b)   [8-wave 128^2]
  gemm_bt8<<<dim3(8, 8, 4), 512, 0, stream>>>(W12 + MW, G, S,
                                              1024, 1024, 1024, 1024,
                                              0, MW, MW);
  // PT_b = NT(S_b, W1)   [8-wave 128^2]
  gemm_bt8<<<dim3(8, 8, 4), 512, 0, stream>>>(S, W12, PT,
                                              1024, 1024, 1024, 1024,
                                              MW, 0, MW);
  // out_b = x_b @ P_b on the 8-phase 256^2 kernel (f32 out)
  gemm256_out<<<dim3(4, 64), 512, 0, stream>>>(xb, PT, out);
}

// Round 12
// 148.194 us; speedup vs baseline: 1.0557x; 1.0557x over previous
//
#include <hip/hip_runtime.h>
#include <hip/hip_bf16.h>
#include <stdint.h>

typedef unsigned short u16;
typedef short bf16x8 __attribute__((ext_vector_type(8)));
typedef float f32x4 __attribute__((ext_vector_type(4)));

#define GLOAD16(gp, lp) __builtin_amdgcn_global_load_lds( \
    (const __attribute__((address_space(1))) uint32_t*)(gp), \
    (__attribute__((address_space(3))) uint32_t*)(lp), 16, 0, 0)

#define VMCNT10 do { asm volatile("s_waitcnt vmcnt(10)" ::: "memory"); \
                     __builtin_amdgcn_sched_barrier(0); } while (0)
#define SBAR    do { __builtin_amdgcn_s_barrier(); \
                     __builtin_amdgcn_sched_barrier(0); } while (0)
#define LGKM0   do { asm volatile("s_waitcnt lgkmcnt(0)" ::: "memory"); \
                     __builtin_amdgcn_sched_barrier(0); } while (0)

__device__ __forceinline__ u16 f2bf(float f) {
  union { float f; uint32_t u; } x; x.f = f;
  return (u16)((x.u + 0x7FFFu + ((x.u >> 16) & 1u)) >> 16);
}
__device__ __forceinline__ float bf2f(u16 h) {
  union { uint32_t u; float f; } x; x.u = (uint32_t)h << 16;
  return x.f;
}

// Bijective XCD-chunked block swizzle (T1, m204 form). Requires nwg % 8 == 0.
__device__ __forceinline__ void xcd_swizzle(int& bx, int& by, int& bz) {
  const int gx = gridDim.x, gy = gridDim.y;
  const int nwg = gx * gy * (int)gridDim.z;
  const int lin = ((int)blockIdx.z * gy + (int)blockIdx.y) * gx + (int)blockIdx.x;
  const int q = nwg >> 3;
  const int wl = (lin & 7) * q + (lin >> 3);
  bz = wl / (gx * gy);
  const int rem = wl - bz * gx * gy;
  by = rem / gx;
  bx = rem - by * gx;
}

// ======= fused cast: x -> xb (rows) + xTt (blocked transpose) + all weights ===
// 256 blocks x 512 threads, 1 block/CU, 147 KB LDS.
// Phase A: 64 rounds; round j reads x row (t0+j) fully coalesced (float2/lane),
//          writes xb row coalesced, deposits bf16 transposed into LDS
//          (col j XOR-swizzled by ((d>>1)&7)<<3 to spread banks).
// Phase B: 16 rounds; writes 8 contiguous 16 KB xTt tiles (4 KB/round coalesced).
// Then: wq/wk/wv streamed, wo transposed (one 64x64 tile per block).
__global__ __launch_bounds__(512) void cast_x_all(const float* __restrict__ x,
                                                  const float* __restrict__ wq,
                                                  const float* __restrict__ wk,
                                                  const float* __restrict__ wv,
                                                  const float* __restrict__ wo,
                                                  u16* __restrict__ xb,
                                                  u16* __restrict__ xTt,
                                                  u16* __restrict__ WA,
                                                  u16* __restrict__ WBb) {
  __shared__ u16 ldsT[73728];   // [1024 d][72 cols], XOR-swizzled
  const int b = blockIdx.x;     // 0..255 (= tchunk)
  const int t = threadIdx.x;    // 0..511
  const int t0 = b * 64;

  // ---- phase A ----
  const int fA = (t & 7) << 3;        // swizzle for rows d=2t and d=2t+1
  const int d2 = t * 2;
  const int rowA0 = d2 * 72;
  const int rowA1 = rowA0 + 72;
  for (int j = 0; j < 64; ++j) {
    float2 v = *(const float2*)&x[(size_t)(t0 + j) * 1024 + d2];
    u16 p0 = f2bf(v.x), p1 = f2bf(v.y);
    *(uint32_t*)&xb[(size_t)(t0 + j) * 1024 + d2] =
        (uint32_t)p0 | ((uint32_t)p1 << 16);
    const int jc = j ^ fA;
    ldsT[rowA0 + jc] = p0;
    ldsT[rowA1 + jc] = p1;
  }
  __syncthreads();

  // ---- phase B: xTt tiles ----
#pragma unroll
  for (int k = 0; k < 16; ++k) {
    const int idx = k * 4096 + t * 8;   // u16 index into block's 128 KB output
    const int tile = idx >> 13;         // 0..7 (= dtile)
    const int o = idx & 8191;
    const int dl = o >> 6, c = o & 63;
    const int d = tile * 128 + dl;
    const int f = ((dl >> 1) & 7) << 3;
    uint4 val = *(const uint4*)&ldsT[d * 72 + (c ^ f)];
    *(uint4*)&xTt[((size_t)(tile * 256 + b)) * 8192 + dl * 64 + c] = val;
  }

  // ---- weights stream: wq/wk/wv (no LDS) ----
#pragma unroll
  for (int r = 0; r < 3; ++r) {
    const int e = b * 12288 + r * 4096 + t * 8;
    const int w = e >> 20, loc = e & 1048575;
    const float* in = w == 0 ? wq : w == 1 ? wk : wv;
    u16* o2 = w == 0 ? WA : w == 1 ? WBb : WBb + 1048576;
    float4 a = *(const float4*)&in[loc];
    float4 c4 = *(const float4*)&in[loc + 4];
    u16 p[8];
    p[0] = f2bf(a.x);  p[1] = f2bf(a.y);  p[2] = f2bf(a.z);  p[3] = f2bf(a.w);
    p[4] = f2bf(c4.x); p[5] = f2bf(c4.y); p[6] = f2bf(c4.z); p[7] = f2bf(c4.w);
    *(uint4*)&o2[loc] = *(const uint4*)p;
  }

  // ---- wo transpose: one 64x64 tile per block ----
  __syncthreads();                      // phase-B LDS reads done
  float (*tf)[65] = (float(*)[65])ldsT; // 16.6 KB alias
  const int r0 = (b >> 4) * 64, c0 = (b & 15) * 64;
  const int lr = t >> 3, lc = (t & 7) * 8;
  {
    const float* src = wo + (size_t)(r0 + lr) * 1024 + c0 + lc;
    float4 v0 = *(const float4*)&src[0];
    float4 v1 = *(const float4*)&src[4];
    tf[lr][lc + 0] = v0.x; tf[lr][lc + 1] = v0.y;
    tf[lr][lc + 2] = v0.z; tf[lr][lc + 3] = v0.w;
    tf[lr][lc + 4] = v1.x; tf[lr][lc + 5] = v1.y;
    tf[lr][lc + 6] = v1.z; tf[lr][lc + 7] = v1.w;
  }
  __syncthreads();
  {
    u16 tr[8];
#pragma unroll
    for (int j = 0; j < 8; ++j) tr[j] = f2bf(tf[lc + j][lr]);
    u16* dst = WA + 1048576 + (size_t)(c0 + lr) * 1024 + r0 + lc;
    *(uint4*)&dst[0] = *(const uint4*)tr;
  }
}

// ------- fused: triangular Gram split-K (576 blocks) + W12 GEMM (128 blocks) ----
// 8-wave 128^2 NT inner loop, K=1024.
// Gram operands come from blocked xTt tiles: lda=64, kt-step=+8192 elems.
__global__ __launch_bounds__(512) void gram_w12(const u16* __restrict__ xTt,
                                                u16* __restrict__ Gp,
                                                const u16* __restrict__ WA,
                                                const u16* __restrict__ WBb,
                                                u16* __restrict__ W12) {
  __shared__ u16 lds[2 * 8192];
  const int lin = blockIdx.x;
  const int wl = (lin & 7) * 88 + (lin >> 3);   // 704/8 = 88, bijective
  const u16 *Abase, *Bbase;
  u16* Cb;
  int lda, sKt, ldc;
  if (wl < 576) {
    const int z = wl / 36, t5 = wl - z * 36;
    const int b = z >> 2, kc = z & 3;
    int ti = 0;
    while ((ti + 1) * (ti + 2) / 2 <= t5) ++ti;
    const int tj = t5 - ti * (ti + 1) / 2;
    const int tc0 = b * 64 + kc * 16;           // first t-chunk of this z-slice
    Abase = xTt + (size_t)(ti * 256 + tc0) * 8192;
    Bbase = xTt + (size_t)(tj * 256 + tc0) * 8192;
    lda = 64; sKt = 8192;
    Cb = Gp + ((size_t)z * 36 + t5) * 16384;
    ldc = 128;
  } else {
    const int w = wl - 576;
    const int z2 = w >> 6, tl = w & 63;
    const int by = tl >> 3, bx = tl & 7;
    Abase = WA + (size_t)z2 * 1048576 + (size_t)(by * 128) * 1024;
    Bbase = WBb + (size_t)z2 * 1048576 + (size_t)(bx * 128) * 1024;
    lda = 1024; sKt = 64;
    Cb = W12 + (size_t)z2 * 1048576 + (size_t)(by * 128) * 1024 + bx * 128;
    ldc = 1024;
  }

  const int t = threadIdx.x;
  const int l = t & 63;
  const int wid = t >> 6;
  const int wr = wid >> 2, wc = wid & 3;
  const int lr16 = l & 15, hi = l >> 4;

  f32x4 acc[4][2];
#pragma unroll
  for (int m = 0; m < 4; ++m)
#pragma unroll
    for (int n = 0; n < 2; ++n) acc[m][n] = (f32x4){0.f, 0.f, 0.f, 0.f};

  for (int s = 0; s < 16; ++s) {
    __syncthreads();
    const u16* As = Abase + (size_t)s * sKt;
    const u16* Bs = Bbase + (size_t)s * sKt;
#pragma unroll
    for (int i = 0; i < 2; ++i) {
      int slot = i * 512 + t;
      int row = slot >> 3, cp = slot & 7;
      int clog = cp ^ (row & 7);
      GLOAD16(As + (size_t)row * lda + clog * 8, &lds[slot * 8]);
    }
#pragma unroll
    for (int i = 0; i < 2; ++i) {
      int slot = i * 512 + t;
      int row = slot >> 3, cp = slot & 7;
      int clog = cp ^ (row & 7);
      GLOAD16(Bs + (size_t)row * lda + clog * 8, &lds[8192 + slot * 8]);
    }
    asm volatile("s_waitcnt vmcnt(0)" ::: "memory");
    __syncthreads();
#pragma unroll
    for (int ks = 0; ks < 2; ++ks) {
      bf16x8 af[4], bfr[2];
#pragma unroll
      for (int m = 0; m < 4; ++m) {
        int row = wr * 64 + m * 16 + lr16;
        int p = (ks * 4 + hi) ^ (row & 7);
        af[m] = *(const bf16x8*)&lds[row * 64 + p * 8];
      }
#pragma unroll
      for (int n = 0; n < 2; ++n) {
        int row = wc * 32 + n * 16 + lr16;
        int p = (ks * 4 + hi) ^ (row & 7);
        bfr[n] = *(const bf16x8*)&lds[8192 + row * 64 + p * 8];
      }
#pragma unroll
      for (int m = 0; m < 4; ++m)
#pragma unroll
        for (int n = 0; n < 2; ++n)
          acc[m][n] = __builtin_amdgcn_mfma_f32_16x16x32_bf16(af[m], bfr[n], acc[m][n], 0, 0, 0);
    }
  }

#pragma unroll
  for (int m = 0; m < 4; ++m) {
    int row0 = wr * 64 + m * 16 + hi * 4;
#pragma unroll
    for (int n = 0; n < 2; ++n) {
      int col = wc * 32 + n * 16 + lr16;
      f32x4 v = acc[m][n];
#pragma unroll
      for (int r = 0; r < 4; ++r) Cb[(size_t)(row0 + r) * ldc + col] = f2bf(v[r]);
    }
  }
}

// ------- 8-wave 128^2 batched NT GEMM (small matrices) ----
__global__ __launch_bounds__(512) void gemm_bt8(const u16* __restrict__ A,
                                                const u16* __restrict__ B,
                                                u16* __restrict__ C,
                                                int lda, int ldb, int ldc, int K,
                                                size_t sA, size_t sB, size_t sC) {
  __shared__ u16 lds[2 * 8192];
  int bx, by, bz;
  xcd_swizzle(bx, by, bz);
  A += (size_t)bz * sA;
  B += (size_t)bz * sB;
  const int t = threadIdx.x;
  const int l = t & 63;
  const int wid = t >> 6;
  const int wr = wid >> 2, wc = wid & 3;
  const int lr16 = l & 15, hi = l >> 4;
  const int mBase = by * 128;
  const int nBase = bx * 128;

  f32x4 acc[4][2];
#pragma unroll
  for (int m = 0; m < 4; ++m)
#pragma unroll
    for (int n = 0; n < 2; ++n) acc[m][n] = (f32x4){0.f, 0.f, 0.f, 0.f};

  for (int kt = 0; kt < K; kt += 64) {
    __syncthreads();
#pragma unroll
    for (int i = 0; i < 2; ++i) {
      int s = i * 512 + t;
      int row = s >> 3, cp = s & 7;
      int clog = cp ^ (row & 7);
      GLOAD16(A + (size_t)(mBase + row) * lda + kt + clog * 8, &lds[s * 8]);
    }
#pragma unroll
    for (int i = 0; i < 2; ++i) {
      int s = i * 512 + t;
      int row = s >> 3, cp = s & 7;
      int clog = cp ^ (row & 7);
      GLOAD16(B + (size_t)(nBase + row) * ldb + kt + clog * 8, &lds[8192 + s * 8]);
    }
    asm volatile("s_waitcnt vmcnt(0)" ::: "memory");
    __syncthreads();
#pragma unroll
    for (int ks = 0; ks < 2; ++ks) {
      bf16x8 af[4], bfr[2];
#pragma unroll
      for (int m = 0; m < 4; ++m) {
        int row = wr * 64 + m * 16 + lr16;
        int p = (ks * 4 + hi) ^ (row & 7);
        af[m] = *(const bf16x8*)&lds[row * 64 + p * 8];
      }
#pragma unroll
      for (int n = 0; n < 2; ++n) {
        int row = wc * 32 + n * 16 + lr16;
        int p = (ks * 4 + hi) ^ (row & 7);
        bfr[n] = *(const bf16x8*)&lds[8192 + row * 64 + p * 8];
      }
#pragma unroll
      for (int m = 0; m < 4; ++m)
#pragma unroll
        for (int n = 0; n < 2; ++n)
          acc[m][n] = __builtin_amdgcn_mfma_f32_16x16x32_bf16(af[m], bfr[n], acc[m][n], 0, 0, 0);
    }
  }

#pragma unroll
  for (int m = 0; m < 4; ++m) {
    int row0 = mBase + wr * 64 + m * 16 + hi * 4;
#pragma unroll
    for (int n = 0; n < 2; ++n) {
      int col = nBase + wc * 32 + n * 16 + lr16;
      f32x4 v = acc[m][n];
      u16* Cb = C + (size_t)bz * sC;
#pragma unroll
      for (int r = 0; r < 4; ++r) Cb[(size_t)(row0 + r) * ldc + col] = f2bf(v[r]);
    }
  }
}

// ------- reduce 4 kc-partials of tile t, write G + mirrored transpose -------
__global__ __launch_bounds__(256) void reduce_mirror(const u16* __restrict__ Gp,
                                                     u16* __restrict__ G) {
  __shared__ u16 ldsT[128][136];
  const int t5 = blockIdx.x;       // 0..35
  const int b = blockIdx.y;        // 0..3
  int ti = 0;
  while ((ti + 1) * (ti + 2) / 2 <= t5) ++ti;
  const int tj = t5 - ti * (ti + 1) / 2;
  const int tid = threadIdx.x;
  const int rr = tid >> 4, ccc = (tid & 15) * 8;
  u16* Gb = G + (size_t)b * 1048576;
  const size_t ZS = (size_t)36 * 16384;
  const u16* base = Gp + ((size_t)(b * 4) * 36 + t5) * 16384;
#pragma unroll
  for (int i = 0; i < 8; ++i) {
    int row = i * 16 + rr;
    const u16* p = base + row * 128 + ccc;
    u16 a0[8], a1[8], a2[8], a3[8], o[8];
    *(uint4*)a0 = *(const uint4*)&p[0];
    *(uint4*)a1 = *(const uint4*)&p[ZS];
    *(uint4*)a2 = *(const uint4*)&p[2 * ZS];
    *(uint4*)a3 = *(const uint4*)&p[3 * ZS];
#pragma unroll
    for (int j = 0; j < 8; ++j)
      o[j] = f2bf(bf2f(a0[j]) + bf2f(a1[j]) + bf2f(a2[j]) + bf2f(a3[j]));
    *(uint4*)&Gb[(size_t)(ti * 128 + row) * 1024 + tj * 128 + ccc] = *(const uint4*)o;
    *(uint4*)&ldsT[row][ccc] = *(const uint4*)o;
  }
  if (ti != tj) {
    __syncthreads();
#pragma unroll
    for (int i = 0; i < 8; ++i) {
      int row = i * 16 + rr;
      u16 m8[8];
#pragma unroll
      for (int j = 0; j < 8; ++j) m8[j] = ldsT[ccc + j][row];
      *(uint4*)&Gb[(size_t)(tj * 128 + row) * 1024 + ti * 128 + ccc] = *(const uint4*)m8;
    }
  }
}

// =================== 256^2 8-phase NT GEMM core ===================
template <bool F32OUT>
__device__ __forceinline__ void gemm256_core(const u16* __restrict__ A,
                                             const u16* __restrict__ B,
                                             void* __restrict__ C,
                                             int lda, int ldb, int ldc, int K,
                                             int mBase, int nBase, u16* lds) {
  const int t = threadIdx.x;
  const int l = t & 63;
  const int wid = t >> 6;
  const int wr = wid >> 2;
  const int wc = wid & 3;
  const int lr16 = l & 15, hi = l >> 4;
  const int rl0 = t >> 3;
  const int rl1 = rl0 + 64;
  const int cp  = t & 7;
  const int cs  = cp ^ (rl0 & 7);
  const int NT = K >> 6;

  f32x4 acc[8][4];
#pragma unroll
  for (int m = 0; m < 8; ++m)
#pragma unroll
    for (int n = 0; n < 4; ++n) acc[m][n] = (f32x4){0.f, 0.f, 0.f, 0.f};

  auto stage = [&](const u16* g0, int ld, u16* d) {
    GLOAD16(g0 + (size_t)rl0 * ld + cs * 8, d + rl0 * 64 + cp * 8);
    GLOAD16(g0 + (size_t)rl1 * ld + cs * 8, d + rl1 * 64 + cp * 8);
  };
  stage(A + (size_t)mBase * lda,          lda, lds + 0);
  stage(B + (size_t)nBase * ldb,          ldb, lds + 16384);
  stage(B + (size_t)(nBase + 128) * ldb,  ldb, lds + 24576);
  stage(A + (size_t)(mBase + 128) * lda,  lda, lds + 8192);
  stage(B + (size_t)nBase * ldb + 64,         ldb, lds + 32768 + 16384);
  stage(A + (size_t)mBase * lda + 64,         lda, lds + 32768);
  stage(B + (size_t)(nBase + 128) * ldb + 64, ldb, lds + 32768 + 24576);

  bf16x8 af[4][2], b0[2][2], b1[2][2];

  for (int tt = 0; tt < NT; ++tt) {
    const int cur = tt & 1;
    u16* bufA = lds + cur * 32768;
    u16* bufB = bufA + 16384;
    u16* bufN = lds + ((tt + 1) & 1) * 32768;
    int t1 = tt + 1; if (t1 >= NT) t1 -= NT;
    int t2 = tt + 2; if (t2 >= NT) t2 -= NT;
    const int k1 = t1 * 64, k2 = t2 * 64;

    // phase 1: (mh0, nh0)
    VMCNT10;
    SBAR;
    stage(A + (size_t)(mBase + 128) * lda + k1, lda, bufN + 8192);
#pragma unroll
    for (int mi = 0; mi < 4; ++mi) {
      int row = wr * 64 + mi * 16 + lr16;
#pragma unroll
      for (int kk = 0; kk < 2; ++kk) {
        int p = (kk * 4 + hi) ^ (row & 7);
        af[mi][kk] = *(const bf16x8*)&bufA[row * 64 + p * 8];
      }
    }
#pragma unroll
    for (int ni = 0; ni < 2; ++ni) {
      int row = wc * 32 + ni * 16 + lr16;
#pragma unroll
      for (int kk = 0; kk < 2; ++kk) {
        int p = (kk * 4 + hi) ^ (row & 7);
        b0[ni][kk] = *(const bf16x8*)&bufB[row * 64 + p * 8];
      }
    }
    LGKM0;
    __builtin_amdgcn_s_setprio(1);
#pragma unroll
    for (int kk = 0; kk < 2; ++kk)
#pragma unroll
      for (int mi = 0; mi < 4; ++mi)
#pragma unroll
        for (int ni = 0; ni < 2; ++ni)
          acc[mi][ni] = __builtin_amdgcn_mfma_f32_16x16x32_bf16(af[mi][kk], b0[ni][kk], acc[mi][ni], 0, 0, 0);
    __builtin_amdgcn_s_setprio(0);

    // phase 2: (mh0, nh1)
    VMCNT10;
    SBAR;
    stage(B + (size_t)nBase * ldb + k2, ldb, bufB);
#pragma unroll
    for (int ni = 0; ni < 2; ++ni) {
      int row = 128 + wc * 32 + ni * 16 + lr16;
#pragma unroll
      for (int kk = 0; kk < 2; ++kk) {
        int p = (kk * 4 + hi) ^ (row & 7);
        b1[ni][kk] = *(const bf16x8*)&bufB[row * 64 + p * 8];
      }
    }
    LGKM0;
    __builtin_amdgcn_s_setprio(1);
#pragma unroll
    for (int kk = 0; kk < 2; ++kk)
#pragma unroll
      for (int mi = 0; mi < 4; ++mi)
#pragma unroll
        for (int ni = 0; ni < 2; ++ni)
          acc[mi][2 + ni] = __builtin_amdgcn_mfma_f32_16x16x32_bf16(af[mi][kk], b1[ni][kk], acc[mi][2 + ni], 0, 0, 0);
    __builtin_amdgcn_s_setprio(0);

    // phase 3: (mh1, nh1)
    VMCNT10;
    SBAR;
    stage(A + (size_t)mBase * lda + k2, lda, bufA);
#pragma unroll
    for (int mi = 0; mi < 4; ++mi) {
      int row = 128 + wr * 64 + mi * 16 + lr16;
#pragma unroll
      for (int kk = 0; kk < 2; ++kk) {
        int p = (kk * 4 + hi) ^ (row & 7);
        af[mi][kk] = *(const bf16x8*)&bufA[row * 64 + p * 8];
      }
    }
    LGKM0;
    __builtin_amdgcn_s_setprio(1);
#pragma unroll
    for (int kk = 0; kk < 2; ++kk)
#pragma unroll
      for (int mi = 0; mi < 4; ++mi)
#pragma unroll
        for (int ni = 0; ni < 2; ++ni)
          acc[4 + mi][2 + ni] = __builtin_amdgcn_mfma_f32_16x16x32_bf16(af[mi][kk], b1[ni][kk], acc[4 + mi][2 + ni], 0, 0, 0);
    __builtin_amdgcn_s_setprio(0);

    // phase 4: (mh1, nh0)
    SBAR;
    stage(B + (size_t)(nBase + 128) * ldb + k2, ldb, bufB + 8192);
    __builtin_amdgcn_s_setprio(1);
#pragma unroll
    for (int kk = 0; kk < 2; ++kk)
#pragma unroll
      for (int mi = 0; mi < 4; ++mi)
#pragma unroll
        for (int ni = 0; ni < 2; ++ni)
          acc[4 + mi][ni] = __builtin_amdgcn_mfma_f32_16x16x32_bf16(af[mi][kk], b0[ni][kk], acc[4 + mi][ni], 0, 0, 0);
    __builtin_amdgcn_s_setprio(0);
  }

#pragma unroll
  for (int m = 0; m < 8; ++m) {
    int row0 = mBase + (m >> 2) * 128 + wr * 64 + (m & 3) * 16 + hi * 4;
#pragma unroll
    for (int n = 0; n < 4; ++n) {
      int col = nBase + (n >> 1) * 128 + wc * 32 + (n & 1) * 16 + lr16;
      f32x4 v = acc[m][n];
      if (F32OUT) {
        float* Cf = (float*)C;
#pragma unroll
        for (int r = 0; r < 4; ++r) Cf[(size_t)(row0 + r) * ldc + col] = v[r];
      } else {
        u16* Cb = (u16*)C;
#pragma unroll
        for (int r = 0; r < 4; ++r) Cb[(size_t)(row0 + r) * ldc + col] = f2bf(v[r]);
      }
    }
  }
}

// out_b = x_b @ P_b : grid (4,64).
__global__ __launch_bounds__(512) void gemm256_out(const u16* __restrict__ xb,
                                                   const u16* __restrict__ PT,
                                                   float* __restrict__ out) {
  __shared__ u16 lds[65536];
  int bx, by, bz;
  xcd_swizzle(bx, by, bz);
  const u16* Bp = PT + (size_t)(by >> 4) * 1048576;
  gemm256_core<true>(xb, Bp, out, 1024, 1024, 1024, 1024, by * 256, bx * 256, lds);
}

// ---------------- host-side orchestration ----------------
// out_b = x_b @ W1 @ G_b @ W2 ; W1 = wq wk^T, W2 = wv wo, G_b = x_b^T x_b.
extern "C" void kernel_launch(void* const* d_in, const int* in_sizes, int n_in,
                              void* d_out, int out_size, void* d_ws, size_t ws_size,
                              hipStream_t stream) {
  const float* x  = (const float*)d_in[0];
  const float* wq = (const float*)d_in[1];
  const float* wk = (const float*)d_in[2];
  const float* wv = (const float*)d_in[3];
  const float* wo = (const float*)d_in[4];
  float* out = (float*)d_out;

  u16* ws = (u16*)d_ws;
  const size_t MW = 1048576;
  u16* xb  = ws;                    // [16384][1024]
  u16* xTt = ws + 16 * MW;          // [8 dtile][256 tchunk] x 16KB blocked tiles
  u16* WA  = ws + 32 * MW;          // [wq][woT]
  u16* WBb = ws + 34 * MW;          // [wk][wv]
  u16* W12 = ws + 36 * MW;          // [W1][W2T]
  u16* G   = ws + 38 * MW;          // [4][1024][1024]
  u16* S   = ws + 42 * MW;          // [4]
  u16* PT  = ws + 46 * MW;          // [4]
  u16* Gp  = ws + 50 * MW;          // [16][36][128][128] bf16 tri partials

  // fused cast: x -> xb + xTt, all weights (one launch)
  cast_x_all<<<256, 512, 0, stream>>>(x, wq, wk, wv, wo, xb, xTt, WA, WBb);

  // fused: triangular Gram split-K (576) + W12 GEMM (128)
  gram_w12<<<704, 512, 0, stream>>>(xTt, Gp, WA, WBb, W12);
  reduce_mirror<<<dim3(36, 4), 256, 0, stream>>>(Gp, G);

  // S_b = NT(W2T, G_b)   [8-wave 128^2]
  gemm_bt8<<<dim3(8, 8, 4), 512, 0, stream>>>(W12 + MW, G, S,
                                              1024, 1024, 1024, 1024,
                                              0, MW, MW);
  // PT_b = NT(S_b, W1)   [8-wave 128^2]
  gemm_bt8<<<dim3(8, 8, 4), 512, 0, stream>>>(S, W12, PT,
                                              1024, 1024, 1024, 1024,
                                              MW, 0, MW);
  // out_b = x_b @ P_b on the 8-phase 256^2 kernel (f32 out)
  gemm256_out<<<dim3(4, 64), 512, 0, stream>>>(xb, PT, out);
}

// Round 13
// 138.697 us; speedup vs baseline: 1.1280x; 1.0685x over previous
//
#include <hip/hip_runtime.h>
#include <hip/hip_bf16.h>
#include <stdint.h>

typedef unsigned short u16;
typedef short bf16x8 __attribute__((ext_vector_type(8)));
typedef float f32x4 __attribute__((ext_vector_type(4)));

#define GLOAD16(gp, lp) __builtin_amdgcn_global_load_lds( \
    (const __attribute__((address_space(1))) uint32_t*)(gp), \
    (__attribute__((address_space(3))) uint32_t*)(lp), 16, 0, 0)

#define VMCNT10 do { asm volatile("s_waitcnt vmcnt(10)" ::: "memory"); \
                     __builtin_amdgcn_sched_barrier(0); } while (0)
#define SBAR    do { __builtin_amdgcn_s_barrier(); \
                     __builtin_amdgcn_sched_barrier(0); } while (0)
#define LGKM0   do { asm volatile("s_waitcnt lgkmcnt(0)" ::: "memory"); \
                     __builtin_amdgcn_sched_barrier(0); } while (0)

__device__ __forceinline__ u16 f2bf(float f) {
  union { float f; uint32_t u; } x; x.f = f;
  return (u16)((x.u + 0x7FFFu + ((x.u >> 16) & 1u)) >> 16);
}
__device__ __forceinline__ float bf2f(u16 h) {
  union { uint32_t u; float f; } x; x.u = (uint32_t)h << 16;
  return x.f;
}

// Bijective XCD-chunked block swizzle (T1, m204 form). Requires nwg % 8 == 0.
__device__ __forceinline__ void xcd_swizzle(int& bx, int& by, int& bz) {
  const int gx = gridDim.x, gy = gridDim.y;
  const int nwg = gx * gy * (int)gridDim.z;
  const int lin = ((int)blockIdx.z * gy + (int)blockIdx.y) * gx + (int)blockIdx.x;
  const int q = nwg >> 3;
  const int wl = (lin & 7) * q + (lin >> 3);
  bz = wl / (gx * gy);
  const int rem = wl - bz * gx * gy;
  by = rem / gx;
  bx = rem - by * gx;
}

// ======= fused cast: x -> xb (rows) + xTt (blocked transpose) + all weights ===
__global__ __launch_bounds__(512) void cast_x_all(const float* __restrict__ x,
                                                  const float* __restrict__ wq,
                                                  const float* __restrict__ wk,
                                                  const float* __restrict__ wv,
                                                  const float* __restrict__ wo,
                                                  u16* __restrict__ xb,
                                                  u16* __restrict__ xTt,
                                                  u16* __restrict__ WA,
                                                  u16* __restrict__ WBb) {
  __shared__ u16 ldsT[73728];   // [1024 d][72 cols], XOR-swizzled
  const int b = blockIdx.x;     // 0..255 (= tchunk)
  const int t = threadIdx.x;    // 0..511
  const int t0 = b * 64;

  // ---- phase A ----
  const int fA = (t & 7) << 3;
  const int d2 = t * 2;
  const int rowA0 = d2 * 72;
  const int rowA1 = rowA0 + 72;
  for (int j = 0; j < 64; ++j) {
    float2 v = *(const float2*)&x[(size_t)(t0 + j) * 1024 + d2];
    u16 p0 = f2bf(v.x), p1 = f2bf(v.y);
    *(uint32_t*)&xb[(size_t)(t0 + j) * 1024 + d2] =
        (uint32_t)p0 | ((uint32_t)p1 << 16);
    const int jc = j ^ fA;
    ldsT[rowA0 + jc] = p0;
    ldsT[rowA1 + jc] = p1;
  }
  __syncthreads();

  // ---- phase B: xTt tiles ----
#pragma unroll
  for (int k = 0; k < 16; ++k) {
    const int idx = k * 4096 + t * 8;
    const int tile = idx >> 13;
    const int o = idx & 8191;
    const int dl = o >> 6, c = o & 63;
    const int d = tile * 128 + dl;
    const int f = ((dl >> 1) & 7) << 3;
    uint4 val = *(const uint4*)&ldsT[d * 72 + (c ^ f)];
    *(uint4*)&xTt[((size_t)(tile * 256 + b)) * 8192 + dl * 64 + c] = val;
  }

  // ---- weights stream: wq/wk/wv ----
#pragma unroll
  for (int r = 0; r < 3; ++r) {
    const int e = b * 12288 + r * 4096 + t * 8;
    const int w = e >> 20, loc = e & 1048575;
    const float* in = w == 0 ? wq : w == 1 ? wk : wv;
    u16* o2 = w == 0 ? WA : w == 1 ? WBb : WBb + 1048576;
    float4 a = *(const float4*)&in[loc];
    float4 c4 = *(const float4*)&in[loc + 4];
    u16 p[8];
    p[0] = f2bf(a.x);  p[1] = f2bf(a.y);  p[2] = f2bf(a.z);  p[3] = f2bf(a.w);
    p[4] = f2bf(c4.x); p[5] = f2bf(c4.y); p[6] = f2bf(c4.z); p[7] = f2bf(c4.w);
    *(uint4*)&o2[loc] = *(const uint4*)p;
  }

  // ---- wo transpose: one 64x64 tile per block ----
  __syncthreads();
  float (*tf)[65] = (float(*)[65])ldsT;
  const int r0 = (b >> 4) * 64, c0 = (b & 15) * 64;
  const int lr = t >> 3, lc = (t & 7) * 8;
  {
    const float* src = wo + (size_t)(r0 + lr) * 1024 + c0 + lc;
    float4 v0 = *(const float4*)&src[0];
    float4 v1 = *(const float4*)&src[4];
    tf[lr][lc + 0] = v0.x; tf[lr][lc + 1] = v0.y;
    tf[lr][lc + 2] = v0.z; tf[lr][lc + 3] = v0.w;
    tf[lr][lc + 4] = v1.x; tf[lr][lc + 5] = v1.y;
    tf[lr][lc + 6] = v1.z; tf[lr][lc + 7] = v1.w;
  }
  __syncthreads();
  {
    u16 tr[8];
#pragma unroll
    for (int j = 0; j < 8; ++j) tr[j] = f2bf(tf[lc + j][lr]);
    u16* dst = WA + 1048576 + (size_t)(c0 + lr) * 1024 + r0 + lc;
    *(uint4*)&dst[0] = *(const uint4*)tr;
  }
}

// ------- fused: triangular Gram split-K (576 blocks) + W12 GEMM (128 blocks) ----
// high-occupancy single-buffer core (2.75 blocks/CU gives cross-block overlap)
__global__ __launch_bounds__(512) void gram_w12(const u16* __restrict__ xTt,
                                                u16* __restrict__ Gp,
                                                const u16* __restrict__ WA,
                                                const u16* __restrict__ WBb,
                                                u16* __restrict__ W12) {
  __shared__ u16 lds[2 * 8192];
  const int lin = blockIdx.x;
  const int wl = (lin & 7) * 88 + (lin >> 3);
  const u16 *Abase, *Bbase;
  u16* Cb;
  int lda, sKt, ldc;
  if (wl < 576) {
    const int z = wl / 36, t5 = wl - z * 36;
    const int b = z >> 2, kc = z & 3;
    int ti = 0;
    while ((ti + 1) * (ti + 2) / 2 <= t5) ++ti;
    const int tj = t5 - ti * (ti + 1) / 2;
    const int tc0 = b * 64 + kc * 16;
    Abase = xTt + (size_t)(ti * 256 + tc0) * 8192;
    Bbase = xTt + (size_t)(tj * 256 + tc0) * 8192;
    lda = 64; sKt = 8192;
    Cb = Gp + ((size_t)z * 36 + t5) * 16384;
    ldc = 128;
  } else {
    const int w = wl - 576;
    const int z2 = w >> 6, tl = w & 63;
    const int by = tl >> 3, bx = tl & 7;
    Abase = WA + (size_t)z2 * 1048576 + (size_t)(by * 128) * 1024;
    Bbase = WBb + (size_t)z2 * 1048576 + (size_t)(bx * 128) * 1024;
    lda = 1024; sKt = 64;
    Cb = W12 + (size_t)z2 * 1048576 + (size_t)(by * 128) * 1024 + bx * 128;
    ldc = 1024;
  }

  const int t = threadIdx.x;
  const int l = t & 63;
  const int wid = t >> 6;
  const int wr = wid >> 2, wc = wid & 3;
  const int lr16 = l & 15, hi = l >> 4;

  f32x4 acc[4][2];
#pragma unroll
  for (int m = 0; m < 4; ++m)
#pragma unroll
    for (int n = 0; n < 2; ++n) acc[m][n] = (f32x4){0.f, 0.f, 0.f, 0.f};

  for (int s = 0; s < 16; ++s) {
    __syncthreads();
    const u16* As = Abase + (size_t)s * sKt;
    const u16* Bs = Bbase + (size_t)s * sKt;
#pragma unroll
    for (int i = 0; i < 2; ++i) {
      int slot = i * 512 + t;
      int row = slot >> 3, cp = slot & 7;
      int clog = cp ^ (row & 7);
      GLOAD16(As + (size_t)row * lda + clog * 8, &lds[slot * 8]);
    }
#pragma unroll
    for (int i = 0; i < 2; ++i) {
      int slot = i * 512 + t;
      int row = slot >> 3, cp = slot & 7;
      int clog = cp ^ (row & 7);
      GLOAD16(Bs + (size_t)row * lda + clog * 8, &lds[8192 + slot * 8]);
    }
    asm volatile("s_waitcnt vmcnt(0)" ::: "memory");
    __syncthreads();
#pragma unroll
    for (int ks = 0; ks < 2; ++ks) {
      bf16x8 af[4], bfr[2];
#pragma unroll
      for (int m = 0; m < 4; ++m) {
        int row = wr * 64 + m * 16 + lr16;
        int p = (ks * 4 + hi) ^ (row & 7);
        af[m] = *(const bf16x8*)&lds[row * 64 + p * 8];
      }
#pragma unroll
      for (int n = 0; n < 2; ++n) {
        int row = wc * 32 + n * 16 + lr16;
        int p = (ks * 4 + hi) ^ (row & 7);
        bfr[n] = *(const bf16x8*)&lds[8192 + row * 64 + p * 8];
      }
#pragma unroll
      for (int m = 0; m < 4; ++m)
#pragma unroll
        for (int n = 0; n < 2; ++n)
          acc[m][n] = __builtin_amdgcn_mfma_f32_16x16x32_bf16(af[m], bfr[n], acc[m][n], 0, 0, 0);
    }
  }

#pragma unroll
  for (int m = 0; m < 4; ++m) {
    int row0 = wr * 64 + m * 16 + hi * 4;
#pragma unroll
    for (int n = 0; n < 2; ++n) {
      int col = wc * 32 + n * 16 + lr16;
      f32x4 v = acc[m][n];
#pragma unroll
      for (int r = 0; r < 4; ++r) Cb[(size_t)(row0 + r) * ldc + col] = f2bf(v[r]);
    }
  }
}

// ------- 8-wave 128^2 batched NT GEMM, DOUBLE-BUFFERED (T3-min 2-phase) -------
// prologue stages buf0; per iter: issue stage(t+1) -> buf^1, compute(t) from buf,
// one vmcnt(0)+barrier per K-step. Staging latency hides under compute (1 blk/CU).
__global__ __launch_bounds__(512) void gemm_bt8(const u16* __restrict__ A,
                                                const u16* __restrict__ B,
                                                u16* __restrict__ C,
                                                int lda, int ldb, int ldc, int K,
                                                size_t sA, size_t sB, size_t sC) {
  __shared__ u16 lds[4 * 8192];   // 64 KB: buf(2) x [A 8192 | B 8192]
  int bx, by, bz;
  xcd_swizzle(bx, by, bz);
  const u16* Ab = A + (size_t)bz * sA + (size_t)(by * 128) * lda;
  const u16* Bb = B + (size_t)bz * sB + (size_t)(bx * 128) * ldb;
  const int t = threadIdx.x;
  const int l = t & 63;
  const int wid = t >> 6;
  const int wr = wid >> 2, wc = wid & 3;
  const int lr16 = l & 15, hi = l >> 4;

  // staging constants: slot s = i*512+t
  const int r0s = t >> 3, cp = t & 7;
  const int cs = cp ^ (r0s & 7);          // same swizzle for both i (row&7 same)

  auto stage = [&](const u16* gA, const u16* gB, int kt, u16* d) {
#pragma unroll
    for (int i = 0; i < 2; ++i) {
      int row = i * 64 + r0s;
      GLOAD16(gA + (size_t)row * lda + kt + cs * 8, d + (i * 512 + t) * 8);
    }
#pragma unroll
    for (int i = 0; i < 2; ++i) {
      int row = i * 64 + r0s;
      GLOAD16(gB + (size_t)row * ldb + kt + cs * 8, d + 8192 + (i * 512 + t) * 8);
    }
  };

  f32x4 acc[4][2];
#pragma unroll
  for (int m = 0; m < 4; ++m)
#pragma unroll
    for (int n = 0; n < 2; ++n) acc[m][n] = (f32x4){0.f, 0.f, 0.f, 0.f};

  // prologue
  stage(Ab, Bb, 0, lds);
  asm volatile("s_waitcnt vmcnt(0)" ::: "memory");
  __syncthreads();

  int cur = 0;
  for (int kt = 0; kt < K; kt += 64) {
    if (kt + 64 < K) stage(Ab, Bb, kt + 64, lds + (cur ^ 1) * 16384);
    const u16* cb = lds + cur * 16384;
#pragma unroll
    for (int ks = 0; ks < 2; ++ks) {
      bf16x8 af[4], bfr[2];
#pragma unroll
      for (int m = 0; m < 4; ++m) {
        int row = wr * 64 + m * 16 + lr16;
        int p = (ks * 4 + hi) ^ (row & 7);
        af[m] = *(const bf16x8*)&cb[row * 64 + p * 8];
      }
#pragma unroll
      for (int n = 0; n < 2; ++n) {
        int row = wc * 32 + n * 16 + lr16;
        int p = (ks * 4 + hi) ^ (row & 7);
        bfr[n] = *(const bf16x8*)&cb[8192 + row * 64 + p * 8];
      }
      __builtin_amdgcn_s_setprio(1);
#pragma unroll
      for (int m = 0; m < 4; ++m)
#pragma unroll
        for (int n = 0; n < 2; ++n)
          acc[m][n] = __builtin_amdgcn_mfma_f32_16x16x32_bf16(af[m], bfr[n], acc[m][n], 0, 0, 0);
      __builtin_amdgcn_s_setprio(0);
    }
    asm volatile("s_waitcnt vmcnt(0)" ::: "memory");
    __syncthreads();
    cur ^= 1;
  }

#pragma unroll
  for (int m = 0; m < 4; ++m) {
    int row0 = by * 128 + wr * 64 + m * 16 + hi * 4;
#pragma unroll
    for (int n = 0; n < 2; ++n) {
      int col = bx * 128 + wc * 32 + n * 16 + lr16;
      f32x4 v = acc[m][n];
      u16* Cb = C + (size_t)bz * sC;
#pragma unroll
      for (int r = 0; r < 4; ++r) Cb[(size_t)(row0 + r) * ldc + col] = f2bf(v[r]);
    }
  }
}

// ------- reduce 4 kc-partials of tile t, write G + mirrored transpose -------
__global__ __launch_bounds__(256) void reduce_mirror(const u16* __restrict__ Gp,
                                                     u16* __restrict__ G) {
  __shared__ u16 ldsT[128][136];
  const int t5 = blockIdx.x;
  const int b = blockIdx.y;
  int ti = 0;
  while ((ti + 1) * (ti + 2) / 2 <= t5) ++ti;
  const int tj = t5 - ti * (ti + 1) / 2;
  const int tid = threadIdx.x;
  const int rr = tid >> 4, ccc = (tid & 15) * 8;
  u16* Gb = G + (size_t)b * 1048576;
  const size_t ZS = (size_t)36 * 16384;
  const u16* base = Gp + ((size_t)(b * 4) * 36 + t5) * 16384;
#pragma unroll
  for (int i = 0; i < 8; ++i) {
    int row = i * 16 + rr;
    const u16* p = base + row * 128 + ccc;
    u16 a0[8], a1[8], a2[8], a3[8], o[8];
    *(uint4*)a0 = *(const uint4*)&p[0];
    *(uint4*)a1 = *(const uint4*)&p[ZS];
    *(uint4*)a2 = *(const uint4*)&p[2 * ZS];
    *(uint4*)a3 = *(const uint4*)&p[3 * ZS];
#pragma unroll
    for (int j = 0; j < 8; ++j)
      o[j] = f2bf(bf2f(a0[j]) + bf2f(a1[j]) + bf2f(a2[j]) + bf2f(a3[j]));
    *(uint4*)&Gb[(size_t)(ti * 128 + row) * 1024 + tj * 128 + ccc] = *(const uint4*)o;
    *(uint4*)&ldsT[row][ccc] = *(const uint4*)o;
  }
  if (ti != tj) {
    __syncthreads();
#pragma unroll
    for (int i = 0; i < 8; ++i) {
      int row = i * 16 + rr;
      u16 m8[8];
#pragma unroll
      for (int j = 0; j < 8; ++j) m8[j] = ldsT[ccc + j][row];
      *(uint4*)&Gb[(size_t)(tj * 128 + row) * 1024 + ti * 128 + ccc] = *(const uint4*)m8;
    }
  }
}

// =================== 256^2 8-phase NT GEMM core ===================
template <bool F32OUT>
__device__ __forceinline__ void gemm256_core(const u16* __restrict__ A,
                                             const u16* __restrict__ B,
                                             void* __restrict__ C,
                                             int lda, int ldb, int ldc, int K,
                                             int mBase, int nBase, u16* lds) {
  const int t = threadIdx.x;
  const int l = t & 63;
  const int wid = t >> 6;
  const int wr = wid >> 2;
  const int wc = wid & 3;
  const int lr16 = l & 15, hi = l >> 4;
  const int rl0 = t >> 3;
  const int rl1 = rl0 + 64;
  const int cp  = t & 7;
  const int cs  = cp ^ (rl0 & 7);
  const int NT = K >> 6;

  f32x4 acc[8][4];
#pragma unroll
  for (int m = 0; m < 8; ++m)
#pragma unroll
    for (int n = 0; n < 4; ++n) acc[m][n] = (f32x4){0.f, 0.f, 0.f, 0.f};

  auto stage = [&](const u16* g0, int ld, u16* d) {
    GLOAD16(g0 + (size_t)rl0 * ld + cs * 8, d + rl0 * 64 + cp * 8);
    GLOAD16(g0 + (size_t)rl1 * ld + cs * 8, d + rl1 * 64 + cp * 8);
  };
  stage(A + (size_t)mBase * lda,          lda, lds + 0);
  stage(B + (size_t)nBase * ldb,          ldb, lds + 16384);
  stage(B + (size_t)(nBase + 128) * ldb,  ldb, lds + 24576);
  stage(A + (size_t)(mBase + 128) * lda,  lda, lds + 8192);
  stage(B + (size_t)nBase * ldb + 64,         ldb, lds + 32768 + 16384);
  stage(A + (size_t)mBase * lda + 64,         lda, lds + 32768);
  stage(B + (size_t)(nBase + 128) * ldb + 64, ldb, lds + 32768 + 24576);

  bf16x8 af[4][2], b0[2][2], b1[2][2];

  for (int tt = 0; tt < NT; ++tt) {
    const int cur = tt & 1;
    u16* bufA = lds + cur * 32768;
    u16* bufB = bufA + 16384;
    u16* bufN = lds + ((tt + 1) & 1) * 32768;
    int t1 = tt + 1; if (t1 >= NT) t1 -= NT;
    int t2 = tt + 2; if (t2 >= NT) t2 -= NT;
    const int k1 = t1 * 64, k2 = t2 * 64;

    // phase 1: (mh0, nh0)
    VMCNT10;
    SBAR;
    stage(A + (size_t)(mBase + 128) * lda + k1, lda, bufN + 8192);
#pragma unroll
    for (int mi = 0; mi < 4; ++mi) {
      int row = wr * 64 + mi * 16 + lr16;
#pragma unroll
      for (int kk = 0; kk < 2; ++kk) {
        int p = (kk * 4 + hi) ^ (row & 7);
        af[mi][kk] = *(const bf16x8*)&bufA[row * 64 + p * 8];
      }
    }
#pragma unroll
    for (int ni = 0; ni < 2; ++ni) {
      int row = wc * 32 + ni * 16 + lr16;
#pragma unroll
      for (int kk = 0; kk < 2; ++kk) {
        int p = (kk * 4 + hi) ^ (row & 7);
        b0[ni][kk] = *(const bf16x8*)&bufB[row * 64 + p * 8];
      }
    }
    LGKM0;
    __builtin_amdgcn_s_setprio(1);
#pragma unroll
    for (int kk = 0; kk < 2; ++kk)
#pragma unroll
      for (int mi = 0; mi < 4; ++mi)
#pragma unroll
        for (int ni = 0; ni < 2; ++ni)
          acc[mi][ni] = __builtin_amdgcn_mfma_f32_16x16x32_bf16(af[mi][kk], b0[ni][kk], acc[mi][ni], 0, 0, 0);
    __builtin_amdgcn_s_setprio(0);

    // phase 2: (mh0, nh1)
    VMCNT10;
    SBAR;
    stage(B + (size_t)nBase * ldb + k2, ldb, bufB);
#pragma unroll
    for (int ni = 0; ni < 2; ++ni) {
      int row = 128 + wc * 32 + ni * 16 + lr16;
#pragma unroll
      for (int kk = 0; kk < 2; ++kk) {
        int p = (kk * 4 + hi) ^ (row & 7);
        b1[ni][kk] = *(const bf16x8*)&bufB[row * 64 + p * 8];
      }
    }
    LGKM0;
    __builtin_amdgcn_s_setprio(1);
#pragma unroll
    for (int kk = 0; kk < 2; ++kk)
#pragma unroll
      for (int mi = 0; mi < 4; ++mi)
#pragma unroll
        for (int ni = 0; ni < 2; ++ni)
          acc[mi][2 + ni] = __builtin_amdgcn_mfma_f32_16x16x32_bf16(af[mi][kk], b1[ni][kk], acc[mi][2 + ni], 0, 0, 0);
    __builtin_amdgcn_s_setprio(0);

    // phase 3: (mh1, nh1)
    VMCNT10;
    SBAR;
    stage(A + (size_t)mBase * lda + k2, lda, bufA);
#pragma unroll
    for (int mi = 0; mi < 4; ++mi) {
      int row = 128 + wr * 64 + mi * 16 + lr16;
#pragma unroll
      for (int kk = 0; kk < 2; ++kk) {
        int p = (kk * 4 + hi) ^ (row & 7);
        af[mi][kk] = *(const bf16x8*)&bufA[row * 64 + p * 8];
      }
    }
    LGKM0;
    __builtin_amdgcn_s_setprio(1);
#pragma unroll
    for (int kk = 0; kk < 2; ++kk)
#pragma unroll
      for (int mi = 0; mi < 4; ++mi)
#pragma unroll
        for (int ni = 0; ni < 2; ++ni)
          acc[4 + mi][2 + ni] = __builtin_amdgcn_mfma_f32_16x16x32_bf16(af[mi][kk], b1[ni][kk], acc[4 + mi][2 + ni], 0, 0, 0);
    __builtin_amdgcn_s_setprio(0);

    // phase 4: (mh1, nh0)
    SBAR;
    stage(B + (size_t)(nBase + 128) * ldb + k2, ldb, bufB + 8192);
    __builtin_amdgcn_s_setprio(1);
#pragma unroll
    for (int kk = 0; kk < 2; ++kk)
#pragma unroll
      for (int mi = 0; mi < 4; ++mi)
#pragma unroll
        for (int ni = 0; ni < 2; ++ni)
          acc[4 + mi][ni] = __builtin_amdgcn_mfma_f32_16x16x32_bf16(af[mi][kk], b0[ni][kk], acc[4 + mi][ni], 0, 0, 0);
    __builtin_amdgcn_s_setprio(0);
  }

#pragma unroll
  for (int m = 0; m < 8; ++m) {
    int row0 = mBase + (m >> 2) * 128 + wr * 64 + (m & 3) * 16 + hi * 4;
#pragma unroll
    for (int n = 0; n < 4; ++n) {
      int col = nBase + (n >> 1) * 128 + wc * 32 + (n & 1) * 16 + lr16;
      f32x4 v = acc[m][n];
      if (F32OUT) {
        float* Cf = (float*)C;
#pragma unroll
        for (int r = 0; r < 4; ++r) Cf[(size_t)(row0 + r) * ldc + col] = v[r];
      } else {
        u16* Cb = (u16*)C;
#pragma unroll
        for (int r = 0; r < 4; ++r) Cb[(size_t)(row0 + r) * ldc + col] = f2bf(v[r]);
      }
    }
  }
}

// out_b = x_b @ P_b : grid (4,64).
__global__ __launch_bounds__(512) void gemm256_out(const u16* __restrict__ xb,
                                                   const u16* __restrict__ PT,
                                                   float* __restrict__ out) {
  __shared__ u16 lds[65536];
  int bx, by, bz;
  xcd_swizzle(bx, by, bz);
  const u16* Bp = PT + (size_t)(by >> 4) * 1048576;
  gemm256_core<true>(xb, Bp, out, 1024, 1024, 1024, 1024, by * 256, bx * 256, lds);
}

// ---------------- host-side orchestration ----------------
// out_b = x_b @ W1 @ G_b @ W2 ; W1 = wq wk^T, W2 = wv wo, G_b = x_b^T x_b.
extern "C" void kernel_launch(void* const* d_in, const int* in_sizes, int n_in,
                              void* d_out, int out_size, void* d_ws, size_t ws_size,
                              hipStream_t stream) {
  const float* x  = (const float*)d_in[0];
  const float* wq = (const float*)d_in[1];
  const float* wk = (const float*)d_in[2];
  const float* wv = (const float*)d_in[3];
  const float* wo = (const float*)d_in[4];
  float* out = (float*)d_out;

  u16* ws = (u16*)d_ws;
  const size_t MW = 1048576;
  u16* xb  = ws;                    // [16384][1024]
  u16* xTt = ws + 16 * MW;          // blocked transpose tiles
  u16* WA  = ws + 32 * MW;          // [wq][woT]
  u16* WBb = ws + 34 * MW;          // [wk][wv]
  u16* W12 = ws + 36 * MW;          // [W1][W2T]
  u16* G   = ws + 38 * MW;          // [4][1024][1024]
  u16* S   = ws + 42 * MW;          // [4]
  u16* PT  = ws + 46 * MW;          // [4]
  u16* Gp  = ws + 50 * MW;          // [16][36][128][128] bf16 tri partials

  // fused cast: x -> xb + xTt, all weights (one launch)
  cast_x_all<<<256, 512, 0, stream>>>(x, wq, wk, wv, wo, xb, xTt, WA, WBb);

  // fused: triangular Gram split-K (576) + W12 GEMM (128)
  gram_w12<<<704, 512, 0, stream>>>(xTt, Gp, WA, WBb, W12);
  reduce_mirror<<<dim3(36, 4), 256, 0, stream>>>(Gp, G);

  // S_b = NT(W2T, G_b)   [8-wave 128^2, double-buffered]
  gemm_bt8<<<dim3(8, 8, 4), 512, 0, stream>>>(W12 + MW, G, S,
                                              1024, 1024, 1024, 1024,
                                              0, MW, MW);
  // PT_b = NT(S_b, W1)   [8-wave 128^2, double-buffered]
  gemm_bt8<<<dim3(8, 8, 4), 512, 0, stream>>>(S, W12, PT,
                                              1024, 1024, 1024, 1024,
                                              MW, 0, MW);
  // out_b = x_b @ P_b on the 8-phase 256^2 kernel (f32 out)
  gemm256_out<<<dim3(4, 64), 512, 0, stream>>>(xb, PT, out);
}